// Round 2
// baseline (1276.114 us; speedup 1.0000x reference)
//
#include <hip/hip_runtime.h>

#define SENT 0x7f7f7f7f
#define NPTS_TOT 400000

// -------- voxelize FINE scale only: atomicMin cascade, K=8 smallest indices --
__global__ __launch_bounds__(256) void k_voxelize(const float* __restrict__ pts,
                                                  int* __restrict__ slots) {
  int i = blockIdx.x * 256 + threadIdx.x;
  if (i >= NPTS_TOT) return;
  float x = pts[i * 5 + 0];
  float y = pts[i * 5 + 1];
  float z = pts[i * 5 + 2];
  if (!(z >= -5.0f && z < 3.0f)) return;
  float fx = floorf((x - (-51.2f)) / 0.4f);
  float fy = floorf((y - (-51.2f)) / 0.4f);
  if (!(fx >= 0.0f && fx < 256.0f && fy >= 0.0f && fy < 256.0f)) return;
  int vid = (int)fy * 256 + (int)fx;
  int* sl = slots + vid * 8;
  // prefilter: if all 8 slots are real and all < i, i can never be kept.
  // (stale reads only show OLDER = larger values -> skip decision stays valid)
  int mx = sl[0];
#pragma unroll
  for (int k = 1; k < 8; ++k) mx = max(mx, sl[k]);
  if (mx != SENT && i > mx) return;
  int v = i;
#pragma unroll
  for (int k = 0; k < 8; ++k) {
    int old = atomicMin(&sl[k], v);
    if (old == SENT) break;  // filled an empty slot
    v = max(v, old);         // displaced (larger) value cascades on
  }
}

// -------- build coarse scale slots from child scale: 8 smallest of 32 -------
__global__ __launch_bounds__(256) void k_merge(const int* __restrict__ slots_src,
                                               int* __restrict__ slots_dst,
                                               int Gc, int shc) {
  int t = blockIdx.x * 256 + threadIdx.x;
  if (t >= Gc * Gc) return;
  int ix = t & (Gc - 1), iy = t >> shc;
  int Gf = Gc << 1;
  const int* s0 = slots_src + ((iy * 2) * Gf + ix * 2) * 8;
  int c[32];
#pragma unroll
  for (int k = 0; k < 8; ++k) {
    c[k] = s0[k];
    c[8 + k] = s0[8 + k];
    c[16 + k] = s0[Gf * 8 + k];
    c[24 + k] = s0[Gf * 8 + 8 + k];
  }
  int* dst = slots_dst + t * 8;
#pragma unroll
  for (int r = 0; r < 8; ++r) {
    int m = c[0];
#pragma unroll
    for (int j = 1; j < 32; ++j) m = min(m, c[j]);
    dst[r] = m;
    if (m == SENT) {
#pragma unroll
      for (int r2 = r + 1; r2 < 8; ++r2) dst[r2] = SENT;
      return;
    }
    // indices are unique (when m != SENT): clear exactly the picked one
#pragma unroll
    for (int j = 0; j < 32; ++j)
      if (c[j] == m) c[j] = 0x7fffffff;
  }
}

// ------------- pass 1: pre-norm global stats (sum y, sum y^2, count) --------
__global__ __launch_bounds__(64) void k_stats_pre(
    const float* __restrict__ pts, const int* __restrict__ slots,
    const float* __restrict__ w_pre, const float* __restrict__ b_pre,
    float* __restrict__ stats, int G, int gshift, int V, float vs, int slot_ofs,
    int stats_ofs) {
  int lane = threadIdx.x;  // = output channel c
  float wcol[12];
#pragma unroll
  for (int r = 0; r < 12; ++r) wcol[r] = w_pre[r * 64 + lane];
  float bb = b_pre[lane];
  float vhalf = vs * 0.5f;
  float acc1 = 0.f, acc2 = 0.f;
  int accCnt = 0;
  for (int v = blockIdx.x; v < V; v += gridDim.x) {
    const int* sl = slots + slot_ofs + v * 8;
    int idx[8];
#pragma unroll
    for (int k = 0; k < 8; ++k) idx[k] = sl[k];
    int npts = 0;
#pragma unroll
    for (int k = 0; k < 8; ++k) npts += (idx[k] != SENT) ? 1 : 0;
    if (npts == 0) continue;
    float px[8], py[8], pz[8], f0[8], f1[8];
#pragma unroll
    for (int j = 0; j < 8; ++j)
      if (j < npts) {
        const float* p = pts + idx[j] * 5;
        px[j] = p[0]; py[j] = p[1]; pz[j] = p[2]; f0[j] = p[3]; f1[j] = p[4];
      }
    float nf = (float)npts;
    float cx = 0.f, cy = 0.f, cz = 0.f;
#pragma unroll
    for (int j = 0; j < 8; ++j)
      if (j < npts) { cx += px[j]; cy += py[j]; cz += pz[j]; }
    cx /= nf; cy /= nf; cz /= nf;
    float ax = (float)(v & (G - 1)) + vhalf;
    float ay = (float)(v >> gshift) + vhalf;
    float az = 4.0f;  // HEIGHT/2
#pragma unroll
    for (int j = 0; j < 8; ++j)
      if (j < npts) {
        float adx = px[j] - ax, ady = py[j] - ay, adz = pz[j] - az;
        float yraw = bb + f0[j] * wcol[0] + f1[j] * wcol[1] + adx * wcol[2] +
                     ady * wcol[3] + adz * wcol[4] + (px[j] - cx) * wcol[5] +
                     (py[j] - cy) * wcol[6] + (pz[j] - cz) * wcol[7] +
                     cx * wcol[8] + cy * wcol[9] + cz * wcol[10] + nf * wcol[11];
        acc1 += yraw;
        acc2 += yraw * yraw;
      }
    accCnt += npts;
  }
  float* sb = stats + stats_ofs;
  atomicAdd(&sb[lane], acc1);
  atomicAdd(&sb[64 + lane], acc2);
  if (lane == 0) atomicAdd(&sb[128], (float)accCnt);
}

// ------------- pass 2: box-precheck fast path; heavy path only near anchor --
__global__ __launch_bounds__(64) void k_main(
    const float* __restrict__ pts, const int* __restrict__ slots,
    const float* __restrict__ kp, const float* __restrict__ w_pre,
    const float* __restrict__ b_pre, const float* __restrict__ g_pre,
    const float* __restrict__ beta_pre, const float* __restrict__ kpw,
    const float* __restrict__ w_post, const float* __restrict__ b_post,
    float* stats, float* __restrict__ zpre, int G, int gshift, int V, float vs,
    int slot_ofs, int stats_ofs, int zofs) {
  __shared__ float pd[8][5];
  __shared__ float hbuf[8][15];
  __shared__ float sbuf[15][64];
  __shared__ float obuf[64];
  int lane = threadIdx.x;
  float* sb = stats + stats_ofs;
  float cntf = fmaxf(sb[128], 1.0f);
  float ym = sb[lane] / cntf;
  float yvv = sb[64 + lane] / cntf - ym * ym;
  float den = sqrtf(yvv + 1e-5f);
  float gpre = g_pre[lane], bpre = beta_pre[lane];
  float wcol[12];
#pragma unroll
  for (int r = 0; r < 12; ++r) wcol[r] = w_pre[r * 64 + lane];
  float bb = b_pre[lane];
  float bpost = b_post[lane];
  float vhalf = vs * 0.5f;
  float zacc1 = 0.f, zacc2 = 0.f;
  for (int v = blockIdx.x; v < V; v += gridDim.x) {
    int ixv = v & (G - 1);
    int iyv = v >> gshift;
    float ax = (float)ixv + vhalf;
    float ay = (float)iyv + vhalf;
    float az = 4.0f;
    // world-space box of this voxel vs anchor: h>0 needs dist(box,anchor)<1.7
    // (|kp|<=0.7, SIGMA=1). z-gap contributes >=1 -> need dx^2+dy^2 < 1.89.
    float x0 = fmaf((float)ixv, vs, -51.2f);
    float y0 = fmaf((float)iyv, vs, -51.2f);
    float qx = fminf(fmaxf(ax, x0), x0 + vs) - ax;
    float qy = fminf(fmaxf(ay, y0), y0 + vs) - ay;
    bool far = (qx * qx + qy * qy) >= 1.89f;
    float z_out;
    if (far) {
      z_out = bpost;  // h == 0 for every point/kernel-point -> out=0 -> b_post
    } else {
      const int* sl = slots + slot_ofs + v * 8;
      int idx[8];
#pragma unroll
      for (int k = 0; k < 8; ++k) idx[k] = sl[k];
      int npts = 0;
#pragma unroll
      for (int k = 0; k < 8; ++k) npts += (idx[k] != SENT) ? 1 : 0;
      if (npts == 0) {
        z_out = bpost;
      } else {
        __syncthreads();  // previous iteration's LDS reads done
        if (lane < 40) {
          int j = lane / 5, r = lane % 5;
          if (j < npts) pd[j][r] = pts[idx[j] * 5 + r];
        }
        __syncthreads();
        int items = npts * 15;
        int myany = 0;
        for (int t = lane; t < items; t += 64) {
          int j = t / 15, k = t % 15;
          float dx = pd[j][0] - ax - kp[k * 3 + 0];
          float dy = pd[j][1] - ay - kp[k * 3 + 1];
          float dz = pd[j][2] - az - kp[k * 3 + 2];
          float dist = sqrtf(dx * dx + dy * dy + dz * dz + 1e-12f);
          float h = fmaxf(1.0f - dist, 0.0f);  // SIGMA = 1
          hbuf[j][k] = h;
          myany |= (h > 0.0f) ? 1 : 0;
        }
        __syncthreads();
        if (!__any(myany)) {
          z_out = bpost;  // s == 0 -> out == 0 -> z = b_post
        } else {
          float cx = 0.f, cy = 0.f, cz = 0.f;
#pragma unroll
          for (int j = 0; j < 8; ++j)
            if (j < npts) { cx += pd[j][0]; cy += pd[j][1]; cz += pd[j][2]; }
          float nf = (float)npts;
          cx /= nf; cy /= nf; cz /= nf;
          float s[15];
#pragma unroll
          for (int k = 0; k < 15; ++k) s[k] = 0.f;
#pragma unroll
          for (int j = 0; j < 8; ++j)
            if (j < npts) {
              float pxx = pd[j][0], pyy = pd[j][1], pzz = pd[j][2];
              float ff0 = pd[j][3], ff1 = pd[j][4];
              float adx = pxx - ax, ady = pyy - ay, adz = pzz - az;
              float yraw = bb + ff0 * wcol[0] + ff1 * wcol[1] + adx * wcol[2] +
                           ady * wcol[3] + adz * wcol[4] + (pxx - cx) * wcol[5] +
                           (pyy - cy) * wcol[6] + (pzz - cz) * wcol[7] +
                           cx * wcol[8] + cy * wcol[9] + cz * wcol[10] +
                           nf * wcol[11];
              float yn = fmaxf((yraw - ym) / den * gpre + bpre, 0.0f);
#pragma unroll
              for (int k = 0; k < 15; ++k) s[k] += hbuf[j][k] * yn;
            }
#pragma unroll
          for (int k = 0; k < 15; ++k) sbuf[k][lane] = s[k];
          __syncthreads();
          float od = 0.f;
          for (int k = 0; k < 15; ++k) {
#pragma unroll 8
            for (int c = 0; c < 64; ++c)
              od += sbuf[k][c] * kpw[(k * 64 + c) * 64 + lane];
          }
          obuf[lane] = od;
          __syncthreads();
          float zz = bpost;
#pragma unroll 8
          for (int c = 0; c < 64; ++c) zz += obuf[c] * w_post[c * 64 + lane];
          z_out = zz;
          __syncthreads();
        }
      }
    }
    zpre[zofs + v * 64 + lane] = z_out;
    zacc1 += z_out;
    zacc2 += z_out * z_out;
  }
  atomicAdd(&sb[160 + lane], zacc1);
  atomicAdd(&sb[224 + lane], zacc2);
}

// ------------- pass 3: post-norm + relu + [v][c] -> [c][v] transpose --------
__global__ __launch_bounds__(256) void k_finalize(
    const float* __restrict__ zpre, const float* __restrict__ stats,
    const float* __restrict__ g_post, const float* __restrict__ beta_post,
    float* __restrict__ out, int V, int zofs, int oofs, int stats_ofs) {
  __shared__ float tile[64][65];
  int tid = threadIdx.x;
  int v0 = blockIdx.x * 64;
  const float* sb = stats + stats_ofs;
  float Vf = (float)V;
#pragma unroll
  for (int it = 0; it < 16; ++it) {
    int lin = it * 256 + tid;
    int vv = lin >> 6, d = lin & 63;
    tile[vv][d] = zpre[zofs + (v0 + vv) * 64 + d];
  }
  __syncthreads();
  int j = tid & 63;
  int dq = tid >> 6;
#pragma unroll
  for (int it = 0; it < 16; ++it) {
    int d = it * 4 + dq;
    float zm = sb[160 + d] / Vf;
    float zv = sb[224 + d] / Vf - zm * zm;
    float dn = sqrtf(zv + 1e-5f);
    float val = (tile[j][d] - zm) / dn * g_post[d] + beta_post[d];
    out[oofs + d * V + v0 + j] = fmaxf(val, 0.0f);
  }
}

extern "C" void kernel_launch(void* const* d_in, const int* in_sizes, int n_in,
                              void* d_out, int out_size, void* d_ws,
                              size_t ws_size, hipStream_t stream) {
  (void)in_sizes; (void)n_in; (void)out_size; (void)ws_size;
  const float* pts       = (const float*)d_in[0];
  const float* kp        = (const float*)d_in[1];
  const float* w_pre     = (const float*)d_in[2];
  const float* b_pre     = (const float*)d_in[3];
  const float* g_pre     = (const float*)d_in[4];
  const float* beta_pre  = (const float*)d_in[5];
  const float* kpw       = (const float*)d_in[6];
  const float* w_post    = (const float*)d_in[7];
  const float* b_post    = (const float*)d_in[8];
  const float* g_post    = (const float*)d_in[9];
  const float* beta_post = (const float*)d_in[10];
  float* out = (float*)d_out;

  int* slots   = (int*)d_ws;                       // 696320 ints (4 scales)
  float* stats = (float*)((char*)d_ws + 2785280);  // 4 x 320 floats
  float* zpre  = (float*)((char*)d_ws + 2790400);  // 87040 x 64 floats

  // only the fine-scale slots need the sentinel fill; coarse are fully written
  hipMemsetAsync(slots, 0x7f, 524288 * 4, stream);
  hipMemsetAsync(stats, 0, 1280 * 4, stream);

  k_voxelize<<<(NPTS_TOT + 255) / 256, 256, 0, stream>>>(pts, slots);

  const int Gs[4]   = {256, 128, 64, 32};
  const int sh[4]   = {8, 7, 6, 5};
  const float vss[4] = {0.4f, 0.8f, 1.6f, 3.2f};
  const int sofs[4] = {0, 524288, 655360, 688128};
  const int vofs[4] = {0, 65536, 81920, 86016};

  // build coarse scales: 8-smallest-of-32 from the 4 children
  for (int s = 1; s < 4; ++s) {
    int Gc = Gs[s];
    k_merge<<<(Gc * Gc + 255) / 256, 256, 0, stream>>>(
        slots + sofs[s - 1], slots + sofs[s], Gc, sh[s]);
  }

  for (int s = 0; s < 4; ++s) {
    int V = Gs[s] * Gs[s];
    int grid = V < 8192 ? V : 8192;
    k_stats_pre<<<grid, 64, 0, stream>>>(pts, slots, w_pre, b_pre, stats, Gs[s],
                                         sh[s], V, vss[s], sofs[s], s * 320);
  }
  for (int s = 0; s < 4; ++s) {
    int V = Gs[s] * Gs[s];
    int grid = V < 8192 ? V : 8192;
    k_main<<<grid, 64, 0, stream>>>(pts, slots, kp, w_pre, b_pre, g_pre,
                                    beta_pre, kpw, w_post, b_post, stats, zpre,
                                    Gs[s], sh[s], V, vss[s], sofs[s], s * 320,
                                    vofs[s] * 64);
  }
  for (int s = 0; s < 4; ++s) {
    int V = Gs[s] * Gs[s];
    k_finalize<<<V / 64, 256, 0, stream>>>(zpre, stats, g_post, beta_post, out,
                                           V, vofs[s] * 64, vofs[s] * 64,
                                           s * 320);
  }
}

// Round 3
// 482.180 us; speedup vs baseline: 2.6465x; 2.6465x over previous
//
#include <hip/hip_runtime.h>

#define SENT 0x7f7f7f7f
#define NPTS_TOT 400000

// -------- voxelize FINE scale only: atomicMin cascade, K=8 smallest indices --
__global__ __launch_bounds__(256) void k_voxelize(const float* __restrict__ pts,
                                                  int* __restrict__ slots) {
  int i = blockIdx.x * 256 + threadIdx.x;
  if (i >= NPTS_TOT) return;
  float x = pts[i * 5 + 0];
  float y = pts[i * 5 + 1];
  float z = pts[i * 5 + 2];
  if (!(z >= -5.0f && z < 3.0f)) return;
  float fx = floorf((x - (-51.2f)) / 0.4f);
  float fy = floorf((y - (-51.2f)) / 0.4f);
  if (!(fx >= 0.0f && fx < 256.0f && fy >= 0.0f && fy < 256.0f)) return;
  int vid = (int)fy * 256 + (int)fx;
  int* sl = slots + vid * 8;
  // prefilter: if all 8 slots are real and all < i, i can never be kept.
  int mx = sl[0];
#pragma unroll
  for (int k = 1; k < 8; ++k) mx = max(mx, sl[k]);
  if (mx != SENT && i > mx) return;
  int v = i;
#pragma unroll
  for (int k = 0; k < 8; ++k) {
    int old = atomicMin(&sl[k], v);
    if (old == SENT) break;  // filled an empty slot
    v = max(v, old);         // displaced (larger) value cascades on
  }
}

// -------- build coarse scale slots from child scale: 8 smallest of 32 -------
__global__ __launch_bounds__(256) void k_merge(const int* __restrict__ slots_src,
                                               int* __restrict__ slots_dst,
                                               int Gc, int shc) {
  int t = blockIdx.x * 256 + threadIdx.x;
  if (t >= Gc * Gc) return;
  int ix = t & (Gc - 1), iy = t >> shc;
  int Gf = Gc << 1;
  const int* s0 = slots_src + ((iy * 2) * Gf + ix * 2) * 8;
  int c[32];
#pragma unroll
  for (int k = 0; k < 8; ++k) {
    c[k] = s0[k];
    c[8 + k] = s0[8 + k];
    c[16 + k] = s0[Gf * 8 + k];
    c[24 + k] = s0[Gf * 8 + 8 + k];
  }
  int* dst = slots_dst + t * 8;
#pragma unroll
  for (int r = 0; r < 8; ++r) {
    int m = c[0];
#pragma unroll
    for (int j = 1; j < 32; ++j) m = min(m, c[j]);
    dst[r] = m;
    if (m == SENT) {
#pragma unroll
      for (int r2 = r + 1; r2 < 8; ++r2) dst[r2] = SENT;
      return;
    }
#pragma unroll
    for (int j = 0; j < 32; ++j)
      if (c[j] == m) c[j] = 0x7fffffff;
  }
}

// ------------- pass 1: pre-norm stats partials (sum y, sum y^2, count) ------
__global__ __launch_bounds__(64) void k_stats_pre(
    const float* __restrict__ pts, const int* __restrict__ slots,
    const float* __restrict__ w_pre, const float* __restrict__ b_pre,
    float* __restrict__ partials, int G, int gshift, int V, float vs,
    int slot_ofs, int part_ofs) {
  int lane = threadIdx.x;  // = output channel c
  float wcol[12];
#pragma unroll
  for (int r = 0; r < 12; ++r) wcol[r] = w_pre[r * 64 + lane];
  float bb = b_pre[lane];
  float vhalf = vs * 0.5f;
  float acc1 = 0.f, acc2 = 0.f;
  int accCnt = 0;
  for (int v = blockIdx.x; v < V; v += gridDim.x) {
    const int* sl = slots + slot_ofs + v * 8;
    int idx[8];
#pragma unroll
    for (int k = 0; k < 8; ++k) idx[k] = sl[k];
    int npts = 0;
#pragma unroll
    for (int k = 0; k < 8; ++k) npts += (idx[k] != SENT) ? 1 : 0;
    if (npts == 0) continue;
    float px[8], py[8], pz[8], f0[8], f1[8];
#pragma unroll
    for (int j = 0; j < 8; ++j)
      if (j < npts) {
        const float* p = pts + idx[j] * 5;
        px[j] = p[0]; py[j] = p[1]; pz[j] = p[2]; f0[j] = p[3]; f1[j] = p[4];
      }
    float nf = (float)npts;
    float cx = 0.f, cy = 0.f, cz = 0.f;
#pragma unroll
    for (int j = 0; j < 8; ++j)
      if (j < npts) { cx += px[j]; cy += py[j]; cz += pz[j]; }
    cx /= nf; cy /= nf; cz /= nf;
    float ax = (float)(v & (G - 1)) + vhalf;
    float ay = (float)(v >> gshift) + vhalf;
    float az = 4.0f;  // HEIGHT/2
#pragma unroll
    for (int j = 0; j < 8; ++j)
      if (j < npts) {
        float adx = px[j] - ax, ady = py[j] - ay, adz = pz[j] - az;
        float yraw = bb + f0[j] * wcol[0] + f1[j] * wcol[1] + adx * wcol[2] +
                     ady * wcol[3] + adz * wcol[4] + (px[j] - cx) * wcol[5] +
                     (py[j] - cy) * wcol[6] + (pz[j] - cz) * wcol[7] +
                     cx * wcol[8] + cy * wcol[9] + cz * wcol[10] + nf * wcol[11];
        acc1 += yraw;
        acc2 += yraw * yraw;
      }
    accCnt += npts;
  }
  float* pb = partials + (part_ofs + blockIdx.x) * 130;
  pb[lane] = acc1;
  pb[64 + lane] = acc2;
  if (lane == 0) pb[128] = (float)accCnt;
}

// --------- reduce partials -> stats. grid = 4 blocks (one per scale) --------
__global__ __launch_bounds__(1024) void k_reduce(
    const float* __restrict__ pp, float* __restrict__ stats, int stride,
    int statbase, int hasCnt, int nb0, int nb1, int nb2, int nb3, int o0,
    int o1, int o2, int o3) {
  int s = blockIdx.x;
  int nb = s == 0 ? nb0 : s == 1 ? nb1 : s == 2 ? nb2 : nb3;
  int base = s == 0 ? o0 : s == 1 ? o1 : s == 2 ? o2 : o3;
  int c = threadIdx.x & 63, w = threadIdx.x >> 6;
  float a1 = 0.f, a2 = 0.f, cn = 0.f;
  for (int b = w; b < nb; b += 16) {
    const float* p = pp + (base + b) * stride;
    a1 += p[c];
    a2 += p[64 + c];
    if (hasCnt && c == 0) cn += p[128];
  }
  float* sb = stats + s * 320 + statbase;
  atomicAdd(&sb[c], a1);
  atomicAdd(&sb[64 + c], a2);
  if (hasCnt && c == 0) atomicAdd(stats + s * 320 + 128, cn);
}

// ------------- pass 2: box-precheck fast path; heavy path only near anchor --
__global__ __launch_bounds__(64) void k_main(
    const float* __restrict__ pts, const int* __restrict__ slots,
    const float* __restrict__ kp, const float* __restrict__ w_pre,
    const float* __restrict__ b_pre, const float* __restrict__ g_pre,
    const float* __restrict__ beta_pre, const float* __restrict__ kpw,
    const float* __restrict__ w_post, const float* __restrict__ b_post,
    const float* __restrict__ stats, float* __restrict__ zpartials,
    float* __restrict__ zpre, int G, int gshift, int V, float vs, int slot_ofs,
    int stats_ofs, int zofs, int part_ofs) {
  __shared__ float pd[8][5];
  __shared__ float hbuf[8][15];
  __shared__ float sbuf[15][64];
  __shared__ float obuf[64];
  int lane = threadIdx.x;
  const float* sb = stats + stats_ofs;
  float cntf = fmaxf(sb[128], 1.0f);
  float ym = sb[lane] / cntf;
  float yvv = sb[64 + lane] / cntf - ym * ym;
  float den = sqrtf(yvv + 1e-5f);
  float gpre = g_pre[lane], bpre = beta_pre[lane];
  float wcol[12];
#pragma unroll
  for (int r = 0; r < 12; ++r) wcol[r] = w_pre[r * 64 + lane];
  float bb = b_pre[lane];
  float bpost = b_post[lane];
  float vhalf = vs * 0.5f;
  float zacc1 = 0.f, zacc2 = 0.f;
  for (int v = blockIdx.x; v < V; v += gridDim.x) {
    int ixv = v & (G - 1);
    int iyv = v >> gshift;
    float ax = (float)ixv + vhalf;
    float ay = (float)iyv + vhalf;
    float az = 4.0f;
    // world-space box of this voxel vs anchor: h>0 needs dist(box,anchor)<1.7
    // (|kp|<=0.7, SIGMA=1). z-gap contributes >=1 -> need dx^2+dy^2 < 1.89.
    float x0 = fmaf((float)ixv, vs, -51.2f);
    float y0 = fmaf((float)iyv, vs, -51.2f);
    float qx = fminf(fmaxf(ax, x0), x0 + vs) - ax;
    float qy = fminf(fmaxf(ay, y0), y0 + vs) - ay;
    bool far = (qx * qx + qy * qy) >= 1.89f;
    float z_out;
    if (far) {
      z_out = bpost;  // h == 0 for every point/kernel-point -> out=0 -> b_post
    } else {
      const int* sl = slots + slot_ofs + v * 8;
      int idx[8];
#pragma unroll
      for (int k = 0; k < 8; ++k) idx[k] = sl[k];
      int npts = 0;
#pragma unroll
      for (int k = 0; k < 8; ++k) npts += (idx[k] != SENT) ? 1 : 0;
      if (npts == 0) {
        z_out = bpost;
      } else {
        __syncthreads();  // previous iteration's LDS reads done
        if (lane < 40) {
          int j = lane / 5, r = lane % 5;
          if (j < npts) pd[j][r] = pts[idx[j] * 5 + r];
        }
        __syncthreads();
        int items = npts * 15;
        int myany = 0;
        for (int t = lane; t < items; t += 64) {
          int j = t / 15, k = t % 15;
          float dx = pd[j][0] - ax - kp[k * 3 + 0];
          float dy = pd[j][1] - ay - kp[k * 3 + 1];
          float dz = pd[j][2] - az - kp[k * 3 + 2];
          float dist = sqrtf(dx * dx + dy * dy + dz * dz + 1e-12f);
          float h = fmaxf(1.0f - dist, 0.0f);  // SIGMA = 1
          hbuf[j][k] = h;
          myany |= (h > 0.0f) ? 1 : 0;
        }
        __syncthreads();
        if (!__any(myany)) {
          z_out = bpost;  // s == 0 -> out == 0 -> z = b_post
        } else {
          float cx = 0.f, cy = 0.f, cz = 0.f;
#pragma unroll
          for (int j = 0; j < 8; ++j)
            if (j < npts) { cx += pd[j][0]; cy += pd[j][1]; cz += pd[j][2]; }
          float nf = (float)npts;
          cx /= nf; cy /= nf; cz /= nf;
          float s[15];
#pragma unroll
          for (int k = 0; k < 15; ++k) s[k] = 0.f;
#pragma unroll
          for (int j = 0; j < 8; ++j)
            if (j < npts) {
              float pxx = pd[j][0], pyy = pd[j][1], pzz = pd[j][2];
              float ff0 = pd[j][3], ff1 = pd[j][4];
              float adx = pxx - ax, ady = pyy - ay, adz = pzz - az;
              float yraw = bb + ff0 * wcol[0] + ff1 * wcol[1] + adx * wcol[2] +
                           ady * wcol[3] + adz * wcol[4] + (pxx - cx) * wcol[5] +
                           (pyy - cy) * wcol[6] + (pzz - cz) * wcol[7] +
                           cx * wcol[8] + cy * wcol[9] + cz * wcol[10] +
                           nf * wcol[11];
              float yn = fmaxf((yraw - ym) / den * gpre + bpre, 0.0f);
#pragma unroll
              for (int k = 0; k < 15; ++k) s[k] += hbuf[j][k] * yn;
            }
#pragma unroll
          for (int k = 0; k < 15; ++k) sbuf[k][lane] = s[k];
          __syncthreads();
          float od = 0.f;
          for (int k = 0; k < 15; ++k) {
#pragma unroll 8
            for (int c = 0; c < 64; ++c)
              od += sbuf[k][c] * kpw[(k * 64 + c) * 64 + lane];
          }
          obuf[lane] = od;
          __syncthreads();
          float zz = bpost;
#pragma unroll 8
          for (int c = 0; c < 64; ++c) zz += obuf[c] * w_post[c * 64 + lane];
          z_out = zz;
          __syncthreads();
        }
      }
    }
    zpre[zofs + v * 64 + lane] = z_out;
    zacc1 += z_out;
    zacc2 += z_out * z_out;
  }
  float* pb = zpartials + (part_ofs + blockIdx.x) * 128;
  pb[lane] = zacc1;
  pb[64 + lane] = zacc2;
}

// ------------- pass 3: post-norm + relu + [v][c] -> [c][v] transpose --------
__global__ __launch_bounds__(256) void k_finalize(
    const float* __restrict__ zpre, const float* __restrict__ stats,
    const float* __restrict__ g_post, const float* __restrict__ beta_post,
    float* __restrict__ out, int V, int zofs, int oofs, int stats_ofs) {
  __shared__ float tile[64][65];
  int tid = threadIdx.x;
  int v0 = blockIdx.x * 64;
  const float* sb = stats + stats_ofs;
  float Vf = (float)V;
#pragma unroll
  for (int it = 0; it < 16; ++it) {
    int lin = it * 256 + tid;
    int vv = lin >> 6, d = lin & 63;
    tile[vv][d] = zpre[zofs + (v0 + vv) * 64 + d];
  }
  __syncthreads();
  int j = tid & 63;
  int dq = tid >> 6;
#pragma unroll
  for (int it = 0; it < 16; ++it) {
    int d = it * 4 + dq;
    float zm = sb[160 + d] / Vf;
    float zv = sb[224 + d] / Vf - zm * zm;
    float dn = sqrtf(zv + 1e-5f);
    float val = (tile[j][d] - zm) / dn * g_post[d] + beta_post[d];
    out[oofs + d * V + v0 + j] = fmaxf(val, 0.0f);
  }
}

extern "C" void kernel_launch(void* const* d_in, const int* in_sizes, int n_in,
                              void* d_out, int out_size, void* d_ws,
                              size_t ws_size, hipStream_t stream) {
  (void)in_sizes; (void)n_in; (void)out_size; (void)ws_size;
  const float* pts       = (const float*)d_in[0];
  const float* kp        = (const float*)d_in[1];
  const float* w_pre     = (const float*)d_in[2];
  const float* b_pre     = (const float*)d_in[3];
  const float* g_pre     = (const float*)d_in[4];
  const float* beta_pre  = (const float*)d_in[5];
  const float* kpw       = (const float*)d_in[6];
  const float* w_post    = (const float*)d_in[7];
  const float* b_post    = (const float*)d_in[8];
  const float* g_post    = (const float*)d_in[9];
  const float* beta_post = (const float*)d_in[10];
  float* out = (float*)d_out;

  int* slots    = (int*)d_ws;                        // 696320 ints
  float* stats  = (float*)((char*)d_ws + 2785280);   // 4 x 320 floats
  float* zpre   = (float*)((char*)d_ws + 2790400);   // 87040 x 64 floats
  float* ppre   = (float*)((char*)d_ws + 25072640);  // 3712 x 130 floats
  float* ppost  = (float*)((char*)d_ws + 27002880);  // 3712 x 128 floats
                                                     // end ~28.9 MB

  hipMemsetAsync(slots, 0x7f, 524288 * 4, stream);
  hipMemsetAsync(stats, 0, 1280 * 4, stream);

  k_voxelize<<<(NPTS_TOT + 255) / 256, 256, 0, stream>>>(pts, slots);

  const int Gs[4]    = {256, 128, 64, 32};
  const int sh[4]    = {8, 7, 6, 5};
  const float vss[4] = {0.4f, 0.8f, 1.6f, 3.2f};
  const int sofs[4]  = {0, 524288, 655360, 688128};
  const int vofs[4]  = {0, 65536, 81920, 86016};
  const int grids[4] = {2048, 1024, 512, 128};  // stats/main block counts
  const int pofs[4]  = {0, 2048, 3072, 3584};   // partial-slot base per scale

  // build coarse scales: 8-smallest-of-32 from the 4 children
  for (int s = 1; s < 4; ++s) {
    int Gc = Gs[s];
    k_merge<<<(Gc * Gc + 255) / 256, 256, 0, stream>>>(
        slots + sofs[s - 1], slots + sofs[s], Gc, sh[s]);
  }

  for (int s = 0; s < 4; ++s) {
    int V = Gs[s] * Gs[s];
    k_stats_pre<<<grids[s], 64, 0, stream>>>(pts, slots, w_pre, b_pre, ppre,
                                             Gs[s], sh[s], V, vss[s], sofs[s],
                                             pofs[s]);
  }
  k_reduce<<<4, 1024, 0, stream>>>(ppre, stats, 130, 0, 1, grids[0], grids[1],
                                   grids[2], grids[3], pofs[0], pofs[1],
                                   pofs[2], pofs[3]);

  for (int s = 0; s < 4; ++s) {
    int V = Gs[s] * Gs[s];
    k_main<<<grids[s], 64, 0, stream>>>(pts, slots, kp, w_pre, b_pre, g_pre,
                                        beta_pre, kpw, w_post, b_post, stats,
                                        ppost, zpre, Gs[s], sh[s], V, vss[s],
                                        sofs[s], s * 320, vofs[s] * 64,
                                        pofs[s]);
  }
  k_reduce<<<4, 1024, 0, stream>>>(ppost, stats, 128, 160, 0, grids[0],
                                   grids[1], grids[2], grids[3], pofs[0],
                                   pofs[1], pofs[2], pofs[3]);

  for (int s = 0; s < 4; ++s) {
    int V = Gs[s] * Gs[s];
    k_finalize<<<V / 64, 256, 0, stream>>>(zpre, stats, g_post, beta_post, out,
                                           V, vofs[s] * 64, vofs[s] * 64,
                                           s * 320);
  }
}

// Round 4
// 330.796 us; speedup vs baseline: 3.8577x; 1.4576x over previous
//
#include <hip/hip_runtime.h>

#define SENT 0x7f7f7f7f
#define NPTS_TOT 400000

// -------- voxelize directly at scale 2 (G=64, vs=1.6): K=8 smallest indices -
// Exactness: floor((x+51.2)/1.6f) is the reference's own per-scale formula.
// Cascade conserves the value multiset and keeps the 8 smallest; slot order is
// irrelevant downstream (all consumers are slot-order-invariant sums).
__global__ __launch_bounds__(256) void k_voxelize(const float* __restrict__ pts,
                                                  int* __restrict__ slots) {
  int i = blockIdx.x * 256 + threadIdx.x;
  if (i >= NPTS_TOT) return;
  float x = pts[i * 5 + 0];
  float y = pts[i * 5 + 1];
  float z = pts[i * 5 + 2];
  if (!(z >= -5.0f && z < 3.0f)) return;
  float fx = floorf((x + 51.2f) / 1.6f);
  float fy = floorf((y + 51.2f) / 1.6f);
  if (!(fx >= 0.0f && fx < 64.0f && fy >= 0.0f && fy < 64.0f)) return;
  int vid = (int)fy * 64 + (int)fx;
  int* sl = slots + vid * 8;
  // prefilter: slot values only ever decrease, so a stale max >= current max;
  // skipping only when i > stale_max is always safe.
  int mx = sl[0];
#pragma unroll
  for (int k = 1; k < 8; ++k) mx = max(mx, sl[k]);
  if (mx != SENT && i > mx) return;
  int v = i;
#pragma unroll
  for (int k = 0; k < 8; ++k) {
    int old = atomicMin(&sl[k], v);
    if (old == SENT) break;  // filled an empty slot
    v = max(v, old);         // displaced (larger) value cascades on
  }
}

// -------- build s3 (G=32) from s2 (G=64): 8 smallest of the 4 children's 32 -
__global__ __launch_bounds__(256) void k_merge(const int* __restrict__ slots_src,
                                               int* __restrict__ slots_dst,
                                               int Gc, int shc) {
  int t = blockIdx.x * 256 + threadIdx.x;
  if (t >= Gc * Gc) return;
  int ix = t & (Gc - 1), iy = t >> shc;
  int Gf = Gc << 1;
  const int* s0 = slots_src + ((iy * 2) * Gf + ix * 2) * 8;
  int c[32];
#pragma unroll
  for (int k = 0; k < 8; ++k) {
    c[k] = s0[k];
    c[8 + k] = s0[8 + k];
    c[16 + k] = s0[Gf * 8 + k];
    c[24 + k] = s0[Gf * 8 + 8 + k];
  }
  int* dst = slots_dst + t * 8;
#pragma unroll
  for (int r = 0; r < 8; ++r) {
    int m = c[0];
#pragma unroll
    for (int j = 1; j < 32; ++j) m = min(m, c[j]);
    dst[r] = m;
    if (m == SENT) {
#pragma unroll
      for (int r2 = r + 1; r2 < 8; ++r2) dst[r2] = SENT;
      return;
    }
#pragma unroll
    for (int j = 0; j < 32; ++j)
      if (c[j] == m) c[j] = 0x7fffffff;
  }
}

// ------------- pre-norm stats partials (sum y, sum y^2, count) — s2/s3 only -
__global__ __launch_bounds__(64) void k_stats_pre(
    const float* __restrict__ pts, const int* __restrict__ slots,
    const float* __restrict__ w_pre, const float* __restrict__ b_pre,
    float* __restrict__ partials, int G, int gshift, int V, float vs,
    int slot_ofs, int part_ofs) {
  int lane = threadIdx.x;  // = output channel c
  float wcol[12];
#pragma unroll
  for (int r = 0; r < 12; ++r) wcol[r] = w_pre[r * 64 + lane];
  float bb = b_pre[lane];
  float vhalf = vs * 0.5f;
  float acc1 = 0.f, acc2 = 0.f;
  int accCnt = 0;
  for (int v = blockIdx.x; v < V; v += gridDim.x) {
    const int* sl = slots + slot_ofs + v * 8;
    int idx[8];
#pragma unroll
    for (int k = 0; k < 8; ++k) idx[k] = sl[k];
    int npts = 0;
#pragma unroll
    for (int k = 0; k < 8; ++k) npts += (idx[k] != SENT) ? 1 : 0;
    if (npts == 0) continue;
    float px[8], py[8], pz[8], f0[8], f1[8];
#pragma unroll
    for (int j = 0; j < 8; ++j)
      if (j < npts) {
        const float* p = pts + idx[j] * 5;
        px[j] = p[0]; py[j] = p[1]; pz[j] = p[2]; f0[j] = p[3]; f1[j] = p[4];
      }
    float nf = (float)npts;
    float cx = 0.f, cy = 0.f, cz = 0.f;
#pragma unroll
    for (int j = 0; j < 8; ++j)
      if (j < npts) { cx += px[j]; cy += py[j]; cz += pz[j]; }
    cx /= nf; cy /= nf; cz /= nf;
    float ax = (float)(v & (G - 1)) + vhalf;
    float ay = (float)(v >> gshift) + vhalf;
    float az = 4.0f;  // HEIGHT/2
#pragma unroll
    for (int j = 0; j < 8; ++j)
      if (j < npts) {
        float adx = px[j] - ax, ady = py[j] - ay, adz = pz[j] - az;
        float yraw = bb + f0[j] * wcol[0] + f1[j] * wcol[1] + adx * wcol[2] +
                     ady * wcol[3] + adz * wcol[4] + (px[j] - cx) * wcol[5] +
                     (py[j] - cy) * wcol[6] + (pz[j] - cz) * wcol[7] +
                     cx * wcol[8] + cy * wcol[9] + cz * wcol[10] + nf * wcol[11];
        acc1 += yraw;
        acc2 += yraw * yraw;
      }
    accCnt += npts;
  }
  float* pb = partials + (part_ofs + blockIdx.x) * 130;
  pb[lane] = acc1;
  pb[64 + lane] = acc2;
  if (lane == 0) pb[128] = (float)accCnt;
}

// --------- reduce partials -> stats. grid = 2 blocks (scales 2 and 3) -------
__global__ __launch_bounds__(1024) void k_reduce(
    const float* __restrict__ pp, float* __restrict__ stats, int stride,
    int statbase, int hasCnt, int nb0, int nb1, int o0, int o1) {
  int s = blockIdx.x;  // 0 -> scale2, 1 -> scale3
  int nb = s == 0 ? nb0 : nb1;
  int base = s == 0 ? o0 : o1;
  int c = threadIdx.x & 63, w = threadIdx.x >> 6;
  float a1 = 0.f, a2 = 0.f, cn = 0.f;
  for (int b = w; b < nb; b += 16) {
    const float* p = pp + (base + b) * stride;
    a1 += p[c];
    a2 += p[64 + c];
    if (hasCnt && c == 0) cn += p[128];
  }
  float* sb = stats + (s + 2) * 320 + statbase;
  atomicAdd(&sb[c], a1);
  atomicAdd(&sb[64 + c], a2);
  if (hasCnt && c == 0) atomicAdd(stats + (s + 2) * 320 + 128, cn);
}

// ------------- main pass (s2/s3): box-precheck fast path; heavy path rare ---
__global__ __launch_bounds__(64) void k_main(
    const float* __restrict__ pts, const int* __restrict__ slots,
    const float* __restrict__ kp, const float* __restrict__ w_pre,
    const float* __restrict__ b_pre, const float* __restrict__ g_pre,
    const float* __restrict__ beta_pre, const float* __restrict__ kpw,
    const float* __restrict__ w_post, const float* __restrict__ b_post,
    const float* __restrict__ stats, float* __restrict__ zpartials,
    float* __restrict__ zpre, int G, int gshift, int V, float vs, int slot_ofs,
    int stats_ofs, int zofs, int part_ofs) {
  __shared__ float pd[8][5];
  __shared__ float hbuf[8][15];
  __shared__ float sbuf[15][64];
  __shared__ float obuf[64];
  int lane = threadIdx.x;
  const float* sb = stats + stats_ofs;
  float cntf = fmaxf(sb[128], 1.0f);
  float ym = sb[lane] / cntf;
  float yvv = sb[64 + lane] / cntf - ym * ym;
  float den = sqrtf(yvv + 1e-5f);
  float gpre = g_pre[lane], bpre = beta_pre[lane];
  float wcol[12];
#pragma unroll
  for (int r = 0; r < 12; ++r) wcol[r] = w_pre[r * 64 + lane];
  float bb = b_pre[lane];
  float bpost = b_post[lane];
  float vhalf = vs * 0.5f;
  float zacc1 = 0.f, zacc2 = 0.f;
  for (int v = blockIdx.x; v < V; v += gridDim.x) {
    int ixv = v & (G - 1);
    int iyv = v >> gshift;
    float ax = (float)ixv + vhalf;
    float ay = (float)iyv + vhalf;
    float az = 4.0f;
    // h>0 needs 3D dist(point, anchor+kp)<1 with |kp|<=0.7 and |pz-az|>1
    // -> xy-dist(box, anchor)^2 < 1.7^2 - 1 = 1.89 (necessary condition).
    float x0 = fmaf((float)ixv, vs, -51.2f);
    float y0 = fmaf((float)iyv, vs, -51.2f);
    float qx = fminf(fmaxf(ax, x0), x0 + vs) - ax;
    float qy = fminf(fmaxf(ay, y0), y0 + vs) - ay;
    bool far = (qx * qx + qy * qy) >= 1.89f;
    float z_out;
    if (far) {
      z_out = bpost;  // h == 0 for every point/kernel-point -> out=0 -> b_post
    } else {
      const int* sl = slots + slot_ofs + v * 8;
      int idx[8];
#pragma unroll
      for (int k = 0; k < 8; ++k) idx[k] = sl[k];
      int npts = 0;
#pragma unroll
      for (int k = 0; k < 8; ++k) npts += (idx[k] != SENT) ? 1 : 0;
      if (npts == 0) {
        z_out = bpost;
      } else {
        __syncthreads();  // previous iteration's LDS reads done
        if (lane < 40) {
          int j = lane / 5, r = lane % 5;
          if (j < npts) pd[j][r] = pts[idx[j] * 5 + r];
        }
        __syncthreads();
        int items = npts * 15;
        int myany = 0;
        for (int t = lane; t < items; t += 64) {
          int j = t / 15, k = t % 15;
          float dx = pd[j][0] - ax - kp[k * 3 + 0];
          float dy = pd[j][1] - ay - kp[k * 3 + 1];
          float dz = pd[j][2] - az - kp[k * 3 + 2];
          float dist = sqrtf(dx * dx + dy * dy + dz * dz + 1e-12f);
          float h = fmaxf(1.0f - dist, 0.0f);  // SIGMA = 1
          hbuf[j][k] = h;
          myany |= (h > 0.0f) ? 1 : 0;
        }
        __syncthreads();
        if (!__any(myany)) {
          z_out = bpost;  // s == 0 -> out == 0 -> z = b_post
        } else {
          float cx = 0.f, cy = 0.f, cz = 0.f;
#pragma unroll
          for (int j = 0; j < 8; ++j)
            if (j < npts) { cx += pd[j][0]; cy += pd[j][1]; cz += pd[j][2]; }
          float nf = (float)npts;
          cx /= nf; cy /= nf; cz /= nf;
          float s[15];
#pragma unroll
          for (int k = 0; k < 15; ++k) s[k] = 0.f;
#pragma unroll
          for (int j = 0; j < 8; ++j)
            if (j < npts) {
              float pxx = pd[j][0], pyy = pd[j][1], pzz = pd[j][2];
              float ff0 = pd[j][3], ff1 = pd[j][4];
              float adx = pxx - ax, ady = pyy - ay, adz = pzz - az;
              float yraw = bb + ff0 * wcol[0] + ff1 * wcol[1] + adx * wcol[2] +
                           ady * wcol[3] + adz * wcol[4] + (pxx - cx) * wcol[5] +
                           (pyy - cy) * wcol[6] + (pzz - cz) * wcol[7] +
                           cx * wcol[8] + cy * wcol[9] + cz * wcol[10] +
                           nf * wcol[11];
              float yn = fmaxf((yraw - ym) / den * gpre + bpre, 0.0f);
#pragma unroll
              for (int k = 0; k < 15; ++k) s[k] += hbuf[j][k] * yn;
            }
#pragma unroll
          for (int k = 0; k < 15; ++k) sbuf[k][lane] = s[k];
          __syncthreads();
          float od = 0.f;
          for (int k = 0; k < 15; ++k) {
#pragma unroll 8
            for (int c = 0; c < 64; ++c)
              od += sbuf[k][c] * kpw[(k * 64 + c) * 64 + lane];
          }
          obuf[lane] = od;
          __syncthreads();
          float zz = bpost;
#pragma unroll 8
          for (int c = 0; c < 64; ++c) zz += obuf[c] * w_post[c * 64 + lane];
          z_out = zz;
          __syncthreads();
        }
      }
    }
    zpre[zofs + v * 64 + lane] = z_out;
    zacc1 += z_out;
    zacc2 += z_out * z_out;
  }
  float* pb = zpartials + (part_ofs + blockIdx.x) * 128;
  pb[lane] = zacc1;
  pb[64 + lane] = zacc2;
}

// ------------- finalize (s2/s3): post-norm + relu + [v][c]->[c][v] ----------
__global__ __launch_bounds__(256) void k_finalize(
    const float* __restrict__ zpre, const float* __restrict__ stats,
    const float* __restrict__ g_post, const float* __restrict__ beta_post,
    float* __restrict__ out, int V, int zofs, int oofs, int stats_ofs) {
  __shared__ float tile[64][65];
  int tid = threadIdx.x;
  int v0 = blockIdx.x * 64;
  const float* sb = stats + stats_ofs;
  float Vf = (float)V;
#pragma unroll
  for (int it = 0; it < 16; ++it) {
    int lin = it * 256 + tid;
    int vv = lin >> 6, d = lin & 63;
    tile[vv][d] = zpre[zofs + (v0 + vv) * 64 + d];
  }
  __syncthreads();
  int j = tid & 63;
  int dq = tid >> 6;
#pragma unroll
  for (int it = 0; it < 16; ++it) {
    int d = it * 4 + dq;
    float zm = sb[160 + d] / Vf;
    float zv = sb[224 + d] / Vf - zm * zm;
    float dn = sqrtf(zv + 1e-5f);
    float val = (tile[j][d] - zm) / dn * g_post[d] + beta_post[d];
    out[oofs + d * V + v0 + j] = fmaxf(val, 0.0f);
  }
}

// ------------- s0/s1: no near voxels exist -> z == b_post everywhere --------
// mean(z)=b_post exactly (power-of-2 count, constant value), var=0 exactly ->
// out = relu(beta_post[c]) broadcast. 5120 blocks x 256 thr x float4 = 21 MB.
__global__ __launch_bounds__(256) void k_fill(
    const float* __restrict__ beta_post, float* __restrict__ out) {
  int idx4 = blockIdx.x * 256 + threadIdx.x;   // float4 index, 1310720 total
  int fidx = idx4 * 4;
  int c = (fidx < 4194304) ? (fidx >> 16) : ((fidx - 4194304) >> 14);
  float v = fmaxf(beta_post[c], 0.0f);
  float4 vv = make_float4(v, v, v, v);
  ((float4*)out)[idx4] = vv;
}

extern "C" void kernel_launch(void* const* d_in, const int* in_sizes, int n_in,
                              void* d_out, int out_size, void* d_ws,
                              size_t ws_size, hipStream_t stream) {
  (void)in_sizes; (void)n_in; (void)out_size; (void)ws_size;
  const float* pts       = (const float*)d_in[0];
  const float* kp        = (const float*)d_in[1];
  const float* w_pre     = (const float*)d_in[2];
  const float* b_pre     = (const float*)d_in[3];
  const float* g_pre     = (const float*)d_in[4];
  const float* beta_pre  = (const float*)d_in[5];
  const float* kpw       = (const float*)d_in[6];
  const float* w_post    = (const float*)d_in[7];
  const float* b_post    = (const float*)d_in[8];
  const float* g_post    = (const float*)d_in[9];
  const float* beta_post = (const float*)d_in[10];
  float* out = (float*)d_out;

  int* slots    = (int*)d_ws;                       // s2: 32768 ints (128 KB)
                                                    // s3: +8192 ints (32 KB)
  float* stats  = (float*)((char*)d_ws + 163840);   // 4 x 320 floats
  float* zpre   = (float*)((char*)d_ws + 168960);   // 5120 x 64 floats
  float* ppre   = (float*)((char*)d_ws + 1479680);  // 640 x 130 floats
  float* ppost  = (float*)((char*)d_ws + 1812480);  // 640 x 128 floats

  hipMemsetAsync(slots, 0x7f, 32768 * 4, stream);   // s2 slots only (s3 fully
  hipMemsetAsync(stats, 0, 1280 * 4, stream);       // written by k_merge)

  k_voxelize<<<(NPTS_TOT + 255) / 256, 256, 0, stream>>>(pts, slots);
  k_merge<<<4, 256, 0, stream>>>(slots, slots + 32768, 32, 5);

  // scale 2: G=64, V=4096, vs=1.6, slot_ofs 0,      stats slot 2, part base 0
  // scale 3: G=32, V=1024, vs=3.2, slot_ofs 32768,  stats slot 3, part base 512
  k_stats_pre<<<512, 64, 0, stream>>>(pts, slots, w_pre, b_pre, ppre, 64, 6,
                                      4096, 1.6f, 0, 0);
  k_stats_pre<<<128, 64, 0, stream>>>(pts, slots, w_pre, b_pre, ppre, 32, 5,
                                      1024, 3.2f, 32768, 512);
  k_reduce<<<2, 1024, 0, stream>>>(ppre, stats, 130, 0, 1, 512, 128, 0, 512);

  k_main<<<512, 64, 0, stream>>>(pts, slots, kp, w_pre, b_pre, g_pre, beta_pre,
                                 kpw, w_post, b_post, stats, ppost, zpre, 64, 6,
                                 4096, 1.6f, 0, 640, 0, 0);
  k_main<<<128, 64, 0, stream>>>(pts, slots, kp, w_pre, b_pre, g_pre, beta_pre,
                                 kpw, w_post, b_post, stats, ppost, zpre, 32, 5,
                                 1024, 3.2f, 32768, 960, 262144, 512);
  k_reduce<<<2, 1024, 0, stream>>>(ppost, stats, 128, 160, 0, 512, 128, 0, 512);

  // outputs: s0 [0,4194304) s1 [4194304,5242880) s2 [5242880,5505024)
  //          s3 [5505024,5570560)
  k_fill<<<5120, 256, 0, stream>>>(beta_post, out);
  k_finalize<<<64, 256, 0, stream>>>(zpre, stats, g_post, beta_post, out, 4096,
                                     0, 5242880, 640);
  k_finalize<<<16, 256, 0, stream>>>(zpre, stats, g_post, beta_post, out, 1024,
                                     262144, 5505024, 960);
}

// Round 5
// 183.259 us; speedup vs baseline: 6.9635x; 1.8051x over previous
//
#include <hip/hip_runtime.h>

#define SENT 0x7f7f7f7f
#define NPTS_TOT 400000
#define PH1 65536

// ---- voxelize phase 1 (i < PH1) at s2 (G=64, vs=1.6): atomicMin cascade ----
__global__ __launch_bounds__(256) void k_vox1(const float* __restrict__ pts,
                                              int* __restrict__ slots) {
  int i = blockIdx.x * 256 + threadIdx.x;  // grid covers exactly PH1
  float x = pts[i * 5 + 0];
  float y = pts[i * 5 + 1];
  float z = pts[i * 5 + 2];
  if (!(z >= -5.0f && z < 3.0f)) return;
  float fx = floorf((x + 51.2f) / 1.6f);
  float fy = floorf((y + 51.2f) / 1.6f);
  if (!(fx >= 0.0f && fx < 64.0f && fy >= 0.0f && fy < 64.0f)) return;
  int vid = (int)fy * 64 + (int)fx;
  int* sl = slots + vid * 8;
  // prefilter: slot values only decrease -> stale max >= live max; skipping
  // only when i > stale_max is always safe.
  int mx = sl[0];
#pragma unroll
  for (int k = 1; k < 8; ++k) mx = max(mx, sl[k]);
  if (mx != SENT && i > mx) return;
  int v = i;
#pragma unroll
  for (int k = 0; k < 8; ++k) {
    int old = atomicMin(&sl[k], v);
    if (old == SENT) break;  // filled an empty slot
    v = max(v, old);         // displaced (larger) value cascades on
  }
}

// ---- seal: snapshot per-cell max of 8 slots into a clean, compact array ----
__global__ __launch_bounds__(256) void k_seal(const int* __restrict__ slots,
                                              int* __restrict__ mxArr) {
  int vid = blockIdx.x * 256 + threadIdx.x;  // 4096 total
  const int* sl = slots + vid * 8;
  int mx = sl[0];
#pragma unroll
  for (int k = 1; k < 8; ++k) mx = max(mx, sl[k]);
  mxArr[vid] = mx;  // == SENT iff cell not yet full
}

// ---- voxelize phase 2 (i >= PH1): read clean snapshot; cascade is rare -----
__global__ __launch_bounds__(256) void k_vox2(const float* __restrict__ pts,
                                              int* __restrict__ slots,
                                              const int* __restrict__ mxArr) {
  int i = PH1 + blockIdx.x * 256 + threadIdx.x;
  if (i >= NPTS_TOT) return;
  float x = pts[i * 5 + 0];
  float y = pts[i * 5 + 1];
  float z = pts[i * 5 + 2];
  if (!(z >= -5.0f && z < 3.0f)) return;
  float fx = floorf((x + 51.2f) / 1.6f);
  float fy = floorf((y + 51.2f) / 1.6f);
  if (!(fx >= 0.0f && fx < 64.0f && fy >= 0.0f && fy < 64.0f)) return;
  int vid = (int)fy * 64 + (int)fx;
  // snapshot skip: if cell was full at snapshot with max mxs, and i > mxs,
  // i can never be kept (slot values only decrease). mxs==SENT -> no skip.
  if (i > mxArr[vid]) return;
  int* sl = slots + vid * 8;
  int mx = sl[0];
#pragma unroll
  for (int k = 1; k < 8; ++k) mx = max(mx, sl[k]);
  if (mx != SENT && i > mx) return;
  int v = i;
#pragma unroll
  for (int k = 0; k < 8; ++k) {
    int old = atomicMin(&sl[k], v);
    if (old == SENT) break;
    v = max(v, old);
  }
}

// ---- build s3 (G=32) from s2 (G=64): 8 smallest of the 4 children's 32 -----
__global__ __launch_bounds__(256) void k_merge(const int* __restrict__ slots_src,
                                               int* __restrict__ slots_dst,
                                               int Gc, int shc) {
  int t = blockIdx.x * 256 + threadIdx.x;
  if (t >= Gc * Gc) return;
  int ix = t & (Gc - 1), iy = t >> shc;
  int Gf = Gc << 1;
  const int* s0 = slots_src + ((iy * 2) * Gf + ix * 2) * 8;
  int c[32];
#pragma unroll
  for (int k = 0; k < 8; ++k) {
    c[k] = s0[k];
    c[8 + k] = s0[8 + k];
    c[16 + k] = s0[Gf * 8 + k];
    c[24 + k] = s0[Gf * 8 + 8 + k];
  }
  int* dst = slots_dst + t * 8;
#pragma unroll
  for (int r = 0; r < 8; ++r) {
    int m = c[0];
#pragma unroll
    for (int j = 1; j < 32; ++j) m = min(m, c[j]);
    dst[r] = m;
    if (m == SENT) {
#pragma unroll
      for (int r2 = r + 1; r2 < 8; ++r2) dst[r2] = SENT;
      return;
    }
#pragma unroll
    for (int j = 0; j < 32; ++j)
      if (c[j] == m) c[j] = 0x7fffffff;
  }
}

// ---- fused pre-norm stats partials for s2 (blocks 0..511) + s3 (512..639) --
__global__ __launch_bounds__(64) void k_stats(
    const float* __restrict__ pts, const int* __restrict__ slots,
    const float* __restrict__ w_pre, const float* __restrict__ b_pre,
    float* __restrict__ partials) {
  int b = blockIdx.x;
  int G, gshift, V, slot_ofs, nblocks, bloc;
  float vs;
  if (b < 512) {
    G = 64; gshift = 6; V = 4096; vs = 1.6f; slot_ofs = 0;
    nblocks = 512; bloc = b;
  } else {
    G = 32; gshift = 5; V = 1024; vs = 3.2f; slot_ofs = 32768;
    nblocks = 128; bloc = b - 512;
  }
  int lane = threadIdx.x;  // = output channel c
  float wcol[12];
#pragma unroll
  for (int r = 0; r < 12; ++r) wcol[r] = w_pre[r * 64 + lane];
  float bb = b_pre[lane];
  float vhalf = vs * 0.5f;
  float acc1 = 0.f, acc2 = 0.f;
  int accCnt = 0;
  for (int v = bloc; v < V; v += nblocks) {
    const int* sl = slots + slot_ofs + v * 8;
    int idx[8];
#pragma unroll
    for (int k = 0; k < 8; ++k) idx[k] = sl[k];
    int npts = 0;
#pragma unroll
    for (int k = 0; k < 8; ++k) npts += (idx[k] != SENT) ? 1 : 0;
    if (npts == 0) continue;
    float px[8], py[8], pz[8], f0[8], f1[8];
#pragma unroll
    for (int j = 0; j < 8; ++j)
      if (j < npts) {
        const float* p = pts + idx[j] * 5;
        px[j] = p[0]; py[j] = p[1]; pz[j] = p[2]; f0[j] = p[3]; f1[j] = p[4];
      }
    float nf = (float)npts;
    float cx = 0.f, cy = 0.f, cz = 0.f;
#pragma unroll
    for (int j = 0; j < 8; ++j)
      if (j < npts) { cx += px[j]; cy += py[j]; cz += pz[j]; }
    cx /= nf; cy /= nf; cz /= nf;
    float ax = (float)(v & (G - 1)) + vhalf;
    float ay = (float)(v >> gshift) + vhalf;
    float az = 4.0f;  // HEIGHT/2
#pragma unroll
    for (int j = 0; j < 8; ++j)
      if (j < npts) {
        float adx = px[j] - ax, ady = py[j] - ay, adz = pz[j] - az;
        float yraw = bb + f0[j] * wcol[0] + f1[j] * wcol[1] + adx * wcol[2] +
                     ady * wcol[3] + adz * wcol[4] + (px[j] - cx) * wcol[5] +
                     (py[j] - cy) * wcol[6] + (pz[j] - cz) * wcol[7] +
                     cx * wcol[8] + cy * wcol[9] + cz * wcol[10] + nf * wcol[11];
        acc1 += yraw;
        acc2 += yraw * yraw;
      }
    accCnt += npts;
  }
  float* pb = partials + b * 130;
  pb[lane] = acc1;
  pb[64 + lane] = acc2;
  if (lane == 0) pb[128] = (float)accCnt;
}

// ---- reduce partials -> stats. grid = 2 blocks (scale2, scale3) ------------
__global__ __launch_bounds__(1024) void k_reduce(
    const float* __restrict__ pp, float* __restrict__ stats, int stride,
    int statbase, int hasCnt) {
  int s = blockIdx.x;  // 0 -> scale2, 1 -> scale3
  int nb = s == 0 ? 512 : 128;
  int base = s == 0 ? 0 : 512;
  int c = threadIdx.x & 63, w = threadIdx.x >> 6;
  float a1 = 0.f, a2 = 0.f, cn = 0.f;
  for (int b = w; b < nb; b += 16) {
    const float* p = pp + (base + b) * stride;
    a1 += p[c];
    a2 += p[64 + c];
    if (hasCnt && c == 0) cn += p[128];
  }
  float* sb = stats + (s + 2) * 320 + statbase;
  atomicAdd(&sb[c], a1);
  atomicAdd(&sb[64 + c], a2);
  if (hasCnt && c == 0) atomicAdd(stats + (s + 2) * 320 + 128, cn);
}

// ---- fused main pass s2 (blocks 0..511) + s3 (512..639) --------------------
__global__ __launch_bounds__(64) void k_main(
    const float* __restrict__ pts, const int* __restrict__ slots,
    const float* __restrict__ kp, const float* __restrict__ w_pre,
    const float* __restrict__ b_pre, const float* __restrict__ g_pre,
    const float* __restrict__ beta_pre, const float* __restrict__ kpw,
    const float* __restrict__ w_post, const float* __restrict__ b_post,
    const float* __restrict__ stats, float* __restrict__ zpartials,
    float* __restrict__ zpre) {
  __shared__ float pd[8][5];
  __shared__ float hbuf[8][15];
  __shared__ float sbuf[15][64];
  __shared__ float obuf[64];
  int b = blockIdx.x;
  int G, gshift, V, slot_ofs, stats_ofs, zofs, nblocks, bloc;
  float vs;
  if (b < 512) {
    G = 64; gshift = 6; V = 4096; vs = 1.6f; slot_ofs = 0; stats_ofs = 640;
    zofs = 0; nblocks = 512; bloc = b;
  } else {
    G = 32; gshift = 5; V = 1024; vs = 3.2f; slot_ofs = 32768; stats_ofs = 960;
    zofs = 262144; nblocks = 128; bloc = b - 512;
  }
  int lane = threadIdx.x;
  const float* sb = stats + stats_ofs;
  float cntf = fmaxf(sb[128], 1.0f);
  float ym = sb[lane] / cntf;
  float yvv = sb[64 + lane] / cntf - ym * ym;
  float den = sqrtf(yvv + 1e-5f);
  float gpre = g_pre[lane], bpre = beta_pre[lane];
  float wcol[12];
#pragma unroll
  for (int r = 0; r < 12; ++r) wcol[r] = w_pre[r * 64 + lane];
  float bb = b_pre[lane];
  float bpost = b_post[lane];
  float vhalf = vs * 0.5f;
  float zacc1 = 0.f, zacc2 = 0.f;
  for (int v = bloc; v < V; v += nblocks) {
    int ixv = v & (G - 1);
    int iyv = v >> gshift;
    float ax = (float)ixv + vhalf;
    float ay = (float)iyv + vhalf;
    float az = 4.0f;
    // h>0 needs 3D dist(point, anchor+kp)<1 with |kp|<=0.7; z-gap >= 1
    // -> xy-dist(box, anchor)^2 < 1.7^2 - 1 = 1.89 (necessary condition).
    float x0 = fmaf((float)ixv, vs, -51.2f);
    float y0 = fmaf((float)iyv, vs, -51.2f);
    float qx = fminf(fmaxf(ax, x0), x0 + vs) - ax;
    float qy = fminf(fmaxf(ay, y0), y0 + vs) - ay;
    bool far = (qx * qx + qy * qy) >= 1.89f;
    float z_out;
    if (far) {
      z_out = bpost;  // h == 0 for every point/kernel-point -> out=0 -> b_post
    } else {
      const int* sl = slots + slot_ofs + v * 8;
      int idx[8];
#pragma unroll
      for (int k = 0; k < 8; ++k) idx[k] = sl[k];
      int npts = 0;
#pragma unroll
      for (int k = 0; k < 8; ++k) npts += (idx[k] != SENT) ? 1 : 0;
      if (npts == 0) {
        z_out = bpost;
      } else {
        __syncthreads();  // previous iteration's LDS reads done
        if (lane < 40) {
          int j = lane / 5, r = lane % 5;
          if (j < npts) pd[j][r] = pts[idx[j] * 5 + r];
        }
        __syncthreads();
        int items = npts * 15;
        int myany = 0;
        for (int t = lane; t < items; t += 64) {
          int j = t / 15, k = t % 15;
          float dx = pd[j][0] - ax - kp[k * 3 + 0];
          float dy = pd[j][1] - ay - kp[k * 3 + 1];
          float dz = pd[j][2] - az - kp[k * 3 + 2];
          float dist = sqrtf(dx * dx + dy * dy + dz * dz + 1e-12f);
          float h = fmaxf(1.0f - dist, 0.0f);  // SIGMA = 1
          hbuf[j][k] = h;
          myany |= (h > 0.0f) ? 1 : 0;
        }
        __syncthreads();
        if (!__any(myany)) {
          z_out = bpost;  // s == 0 -> out == 0 -> z = b_post
        } else {
          float cx = 0.f, cy = 0.f, cz = 0.f;
#pragma unroll
          for (int j = 0; j < 8; ++j)
            if (j < npts) { cx += pd[j][0]; cy += pd[j][1]; cz += pd[j][2]; }
          float nf = (float)npts;
          cx /= nf; cy /= nf; cz /= nf;
          float s[15];
#pragma unroll
          for (int k = 0; k < 15; ++k) s[k] = 0.f;
#pragma unroll
          for (int j = 0; j < 8; ++j)
            if (j < npts) {
              float pxx = pd[j][0], pyy = pd[j][1], pzz = pd[j][2];
              float ff0 = pd[j][3], ff1 = pd[j][4];
              float adx = pxx - ax, ady = pyy - ay, adz = pzz - az;
              float yraw = bb + ff0 * wcol[0] + ff1 * wcol[1] + adx * wcol[2] +
                           ady * wcol[3] + adz * wcol[4] + (pxx - cx) * wcol[5] +
                           (pyy - cy) * wcol[6] + (pzz - cz) * wcol[7] +
                           cx * wcol[8] + cy * wcol[9] + cz * wcol[10] +
                           nf * wcol[11];
              float yn = fmaxf((yraw - ym) / den * gpre + bpre, 0.0f);
#pragma unroll
              for (int k = 0; k < 15; ++k) s[k] += hbuf[j][k] * yn;
            }
#pragma unroll
          for (int k = 0; k < 15; ++k) sbuf[k][lane] = s[k];
          __syncthreads();
          float od = 0.f;
          for (int k = 0; k < 15; ++k) {
#pragma unroll 8
            for (int c = 0; c < 64; ++c)
              od += sbuf[k][c] * kpw[(k * 64 + c) * 64 + lane];
          }
          obuf[lane] = od;
          __syncthreads();
          float zz = bpost;
#pragma unroll 8
          for (int c = 0; c < 64; ++c) zz += obuf[c] * w_post[c * 64 + lane];
          z_out = zz;
          __syncthreads();
        }
      }
    }
    zpre[zofs + v * 64 + lane] = z_out;
    zacc1 += z_out;
    zacc2 += z_out * z_out;
  }
  float* pb = zpartials + b * 128;
  pb[lane] = zacc1;
  pb[64 + lane] = zacc2;
}

// ---- fused output: fill s0/s1 (blocks 0..5119) + finalize s2/s3 ------------
// s0/s1 proof: no voxel within 1.374 of its (grid-unit) anchor exists at
// those scales -> h==0 -> z==b_post everywhere -> var=0, mean=b_post exactly
// -> out = relu(beta_post[c]) broadcast.
__global__ __launch_bounds__(256) void k_out(
    const float* __restrict__ zpre, const float* __restrict__ stats,
    const float* __restrict__ g_post, const float* __restrict__ beta_post,
    float* __restrict__ out) {
  __shared__ float tile[64][65];
  int b = blockIdx.x;
  int tid = threadIdx.x;
  if (b < 5120) {  // fill branch: 5120*256 float4 = s0+s1 regions
    int idx4 = b * 256 + tid;
    int fidx = idx4 * 4;
    int c = (fidx < 4194304) ? (fidx >> 16) : ((fidx - 4194304) >> 14);
    float v = fmaxf(beta_post[c], 0.0f);
    ((float4*)out)[idx4] = make_float4(v, v, v, v);
    return;
  }
  int V, zofs, oofs, stats_ofs, v0;
  if (b < 5184) {  // s2 finalize: 64 blocks
    V = 4096; zofs = 0; oofs = 5242880; stats_ofs = 640; v0 = (b - 5120) * 64;
  } else {         // s3 finalize: 16 blocks
    V = 1024; zofs = 262144; oofs = 5505024; stats_ofs = 960;
    v0 = (b - 5184) * 64;
  }
  const float* sb = stats + stats_ofs;
  float Vf = (float)V;
#pragma unroll
  for (int it = 0; it < 16; ++it) {
    int lin = it * 256 + tid;
    int vv = lin >> 6, d = lin & 63;
    tile[vv][d] = zpre[zofs + (v0 + vv) * 64 + d];
  }
  __syncthreads();
  int j = tid & 63;
  int dq = tid >> 6;
#pragma unroll
  for (int it = 0; it < 16; ++it) {
    int d = it * 4 + dq;
    float zm = sb[160 + d] / Vf;
    float zv = sb[224 + d] / Vf - zm * zm;
    float dn = sqrtf(zv + 1e-5f);
    float val = (tile[j][d] - zm) / dn * g_post[d] + beta_post[d];
    out[oofs + d * V + v0 + j] = fmaxf(val, 0.0f);
  }
}

extern "C" void kernel_launch(void* const* d_in, const int* in_sizes, int n_in,
                              void* d_out, int out_size, void* d_ws,
                              size_t ws_size, hipStream_t stream) {
  (void)in_sizes; (void)n_in; (void)out_size; (void)ws_size;
  const float* pts       = (const float*)d_in[0];
  const float* kp        = (const float*)d_in[1];
  const float* w_pre     = (const float*)d_in[2];
  const float* b_pre     = (const float*)d_in[3];
  const float* g_pre     = (const float*)d_in[4];
  const float* beta_pre  = (const float*)d_in[5];
  const float* kpw       = (const float*)d_in[6];
  const float* w_post    = (const float*)d_in[7];
  const float* b_post    = (const float*)d_in[8];
  const float* g_post    = (const float*)d_in[9];
  const float* beta_post = (const float*)d_in[10];
  float* out = (float*)d_out;

  int* slots    = (int*)d_ws;                       // s2: 32768, s3: +8192 ints
  int* mxArr    = (int*)((char*)d_ws + 163840);     // 4096 ints
  float* stats  = (float*)((char*)d_ws + 180224);   // 4 x 320 floats
  float* zpre   = (float*)((char*)d_ws + 185344);   // 5120 x 64 floats
  float* ppre   = (float*)((char*)d_ws + 1496064);  // 640 x 130 floats
  float* ppost  = (float*)((char*)d_ws + 1828864);  // 640 x 128 floats

  hipMemsetAsync(slots, 0x7f, 32768 * 4, stream);  // s2 slots (s3 via merge)
  hipMemsetAsync(stats, 0, 1280 * 4, stream);

  k_vox1<<<PH1 / 256, 256, 0, stream>>>(pts, slots);
  k_seal<<<16, 256, 0, stream>>>(slots, mxArr);
  k_vox2<<<(NPTS_TOT - PH1 + 255) / 256, 256, 0, stream>>>(pts, slots, mxArr);
  k_merge<<<4, 256, 0, stream>>>(slots, slots + 32768, 32, 5);

  k_stats<<<640, 64, 0, stream>>>(pts, slots, w_pre, b_pre, ppre);
  k_reduce<<<2, 1024, 0, stream>>>(ppre, stats, 130, 0, 1);

  k_main<<<640, 64, 0, stream>>>(pts, slots, kp, w_pre, b_pre, g_pre, beta_pre,
                                 kpw, w_post, b_post, stats, ppost, zpre);
  k_reduce<<<2, 1024, 0, stream>>>(ppost, stats, 128, 160, 0);

  // outputs: s0 [0,4194304) s1 [4194304,5242880) s2 [5242880,5505024)
  //          s3 [5505024,5570560)
  k_out<<<5200, 256, 0, stream>>>(zpre, stats, g_post, beta_post, out);
}